// Round 11
// baseline (141.531 us; speedup 1.0000x reference)
//
#include <hip/hip_runtime.h>
#include <stdint.h>

#define NBOX 4096
#define IMG 640.0f

typedef unsigned long long u64;
typedef unsigned int u32;

// ws layout (bytes):
//   [0      .. 16384)    sx1   (4096 f32, sorted)
//   [16384  .. 32768)    sy1
//   [32768  .. 49152)    sx2
//   [49152  .. 65536)    sy2
//   [65536  .. 81920)    sconf
//   [81920  .. 81924)    M (int, zeroed by k_rank blk(0,0); k_scatter accumulates)
//   [86016  .. 118784)   diagR (4096 u64): row r's suppression word within its own diagonal block
//   [131072 .. 2228224)  mask (ROW-major: mask[row][word], 4096 x 64 u64 = 2 MB)
//   [2228224 .. 2490368) rank_partial (16 x 4096 int = 256 KB)

// Grid (16 i-chunks, 16 j-chunks), 256 thr. Partial rank of i within j-chunk.
__global__ __launch_bounds__(256) void k_rank(const float* __restrict__ raw,
                                              int* __restrict__ rank_partial, int* __restrict__ Mp) {
    const int bi = blockIdx.x, bj = blockIdx.y;
    const int t = threadIdx.x;
    const int i = bi * 256 + t;
    if (bi == 0 && bj == 0 && t == 0) *Mp = 0;
    __shared__ float cj[256];
    cj[t] = raw[(bj * 256 + t) * 5 + 4];
    __syncthreads();

    const float ci = raw[i * 5 + 4];
    const int jbase = bj * 256;
    int rank = 0;
    const float4* c4 = reinterpret_cast<const float4*>(cj);
#pragma unroll 4
    for (int j4 = 0; j4 < 64; ++j4) {
        float4 c = c4[j4];
        int j = jbase + j4 * 4;
        rank += (c.x > ci || (c.x == ci && (j + 0) < i)) ? 1 : 0;
        rank += (c.y > ci || (c.y == ci && (j + 1) < i)) ? 1 : 0;
        rank += (c.z > ci || (c.z == ci && (j + 2) < i)) ? 1 : 0;
        rank += (c.w > ci || (c.w == ci && (j + 3) < i)) ? 1 : 0;
    }
    rank_partial[bj * NBOX + i] = rank;
}

__global__ __launch_bounds__(256) void k_scatter(const float* __restrict__ raw,
                                                 const int* __restrict__ rank_partial,
                                                 float* __restrict__ sx1, float* __restrict__ sy1,
                                                 float* __restrict__ sx2, float* __restrict__ sy2,
                                                 float* __restrict__ sconf, int* __restrict__ Mp) {
    const int i = blockIdx.x * 256 + threadIdx.x;
    const float ci = raw[i * 5 + 4];
    const bool vi = (ci >= 0.5f);

    int rank = 0;
#pragma unroll
    for (int k = 0; k < 16; ++k) rank += rank_partial[k * NBOX + i];

    u64 bal = __ballot(vi);
    if ((threadIdx.x & 63) == 0) atomicAdd(Mp, (int)__popcll(bal));

    if (vi) {
        // Strict IEEE ops (no FMA contraction) to match the numpy-evaluated reference.
        float cx = __fmul_rn(raw[i * 5 + 0], IMG);
        float cy = __fmul_rn(raw[i * 5 + 1], IMG);
        float w  = __fmul_rn(raw[i * 5 + 2], IMG);
        float h  = __fmul_rn(raw[i * 5 + 3], IMG);
        float hw = __fmul_rn(w, 0.5f);
        float hh = __fmul_rn(h, 0.5f);
        sx1[rank]   = __fsub_rn(cx, hw);
        sy1[rank]   = __fsub_rn(cy, hh);
        sx2[rank]   = __fadd_rn(cx, hw);
        sy2[rank]   = __fadd_rn(cy, hh);
        sconf[rank] = ci;
    }
}

// Block (bx, w): rows r = bx*256+tid (lane = row), word w of columns.
__global__ __launch_bounds__(256) void k_mask(const float* __restrict__ sx1, const float* __restrict__ sy1,
                                              const float* __restrict__ sx2, const float* __restrict__ sy2,
                                              const int* __restrict__ Mp,
                                              u64* __restrict__ mask, u64* __restrict__ diagR) {
    const int w = blockIdx.y;                      // column word 0..63
    const int r = blockIdx.x * 256 + threadIdx.x;  // row 0..4095
    const int t = threadIdx.x;
    const int M = *Mp;

    __shared__ float cx1[64], cy1[64], cx2[64], cy2[64], car[64];
    if (t < 64) {
        int j = (w << 6) + t;
        float a1 = sx1[j], b1 = sy1[j], a2 = sx2[j], b2 = sy2[j];
        cx1[t] = a1; cy1[t] = b1; cx2[t] = a2; cy2[t] = b2;
        car[t] = __fmul_rn(__fsub_rn(a2, a1), __fsub_rn(b2, b1));
    }
    __syncthreads();

    u64 bits = 0ULL;
    if (r < M) {
        const float x1 = sx1[r], y1 = sy1[r], x2 = sx2[r], y2 = sy2[r];
        const float area_i = __fmul_rn(__fsub_rn(x2, x1), __fsub_rn(y2, y1));
        const int bmax = min(64, M - (w << 6));       // j < M
        const int bmin = max(0, r + 1 - (w << 6));    // j > r
        for (int b = bmin; b < bmax; ++b) {
            float xx1 = fmaxf(x1, cx1[b]);
            float yy1 = fmaxf(y1, cy1[b]);
            float xx2 = fminf(x2, cx2[b]);
            float yy2 = fminf(y2, cy2[b]);
            float iw = fmaxf(__fsub_rn(xx2, xx1), 0.0f);
            float ih = fmaxf(__fsub_rn(yy2, yy1), 0.0f);
            float inter = __fmul_rn(iw, ih);
            float uni = __fsub_rn(__fadd_rn(area_i, car[b]), inter);
            float iou = __fdiv_rn(inter, fmaxf(uni, 1e-9f));
            if (iou > 0.5f) bits |= (1ULL << b);
        }
        mask[((size_t)r << 6) + w] = bits;            // row-major
    }

    // diagonal block: row r's own-word suppression bits (0 for r >= M)
    if ((r >> 6) == w) diagR[r] = bits;
}

// SINGLE-WAVE greedy scan. Lane l holds remv word l in registers.
// NOTE: __builtin_amdgcn_readlane returns *int* -- ALWAYS assign to a u32
// temporary before widening to u64 ((u64)(int) sign-extends: R6/R10 bug).
__global__ __launch_bounds__(256) void k_scan(const int* __restrict__ Mp,
                                              const u64* __restrict__ mask,
                                              const u64* __restrict__ diagR,
                                              const float* __restrict__ sx1, const float* __restrict__ sy1,
                                              const float* __restrict__ sx2, const float* __restrict__ sy2,
                                              const float* __restrict__ sconf,
                                              float* __restrict__ out) {
    __shared__ u64 kbArr[64];
    const int tid = threadIdx.x;
    const int lane = tid & 63;
    const int M = *Mp;
    const int nblk = (M + 63) >> 6;

    if (tid < 64) kbArr[tid] = 0ULL;

    if ((tid >> 6) == 0 && nblk > 0) {
        __builtin_amdgcn_s_setprio(1);
        u64 d = diagR[lane];                          // block 0 diag rows
        u32 dlo = (u32)d, dhi = (u32)(d >> 32);
        u32 rvlo = 0, rvhi = 0;                       // distributed remv word `lane`

        for (int b = 0; b < nblk; ++b) {
            // prefetch next block's diag rows (independent, hidden under resolve+wait)
            u64 nd = (b + 1 < nblk) ? diagR[((b + 1) << 6) + lane] : 0ULL;

            u32 rbl = (u32)__builtin_amdgcn_readlane(rvlo, b);   // u32 temp first!
            u32 rbh = (u32)__builtin_amdgcn_readlane(rvhi, b);
            const u64 rb = ((u64)rbh << 32) | (u64)rbl;
            const int rem = M - (b << 6);
            const u64 valid = (rem >= 64) ? ~0ULL : ((1ULL << rem) - 1ULL);
            u64 alive = valid & ~rb;
            u64 kb = 0ULL;
            while (alive) {                           // uniform; iterate kept boxes only
                int i = __builtin_ctzll(alive);
                alive &= alive - 1;
                kb |= (1ULL << i);
                u32 lo = (u32)__builtin_amdgcn_readlane(dlo, i);
                u32 hi = (u32)__builtin_amdgcn_readlane(dhi, i);
                alive &= ~(((u64)hi << 32) | (u64)lo);   // row i: bits only > i
            }
            if (lane == 0) kbArr[b] = kb;

            // OR kept rows into distributed remv: batches of 8 independent
            // coalesced loads (512 B each), one wait per batch (usually 1 batch).
            u64 t = kb;
            const u64* rowbase = mask + ((size_t)(b << 6) << 6);
            while (t) {
                int i0 = __builtin_ctzll(t); t &= t - 1;
                const bool h1 = t != 0ULL; int i1 = h1 ? __builtin_ctzll(t) : i0; if (h1) t &= t - 1;
                const bool h2 = t != 0ULL; int i2 = h2 ? __builtin_ctzll(t) : i0; if (h2) t &= t - 1;
                const bool h3 = t != 0ULL; int i3 = h3 ? __builtin_ctzll(t) : i0; if (h3) t &= t - 1;
                const bool h4 = t != 0ULL; int i4 = h4 ? __builtin_ctzll(t) : i0; if (h4) t &= t - 1;
                const bool h5 = t != 0ULL; int i5 = h5 ? __builtin_ctzll(t) : i0; if (h5) t &= t - 1;
                const bool h6 = t != 0ULL; int i6 = h6 ? __builtin_ctzll(t) : i0; if (h6) t &= t - 1;
                const bool h7 = t != 0ULL; int i7 = h7 ? __builtin_ctzll(t) : i0; if (h7) t &= t - 1;
                u64 v0 = rowbase[((size_t)i0 << 6) + lane];
                u64 v1 = rowbase[((size_t)i1 << 6) + lane];
                u64 v2 = rowbase[((size_t)i2 << 6) + lane];
                u64 v3 = rowbase[((size_t)i3 << 6) + lane];
                u64 v4 = rowbase[((size_t)i4 << 6) + lane];
                u64 v5 = rowbase[((size_t)i5 << 6) + lane];
                u64 v6 = rowbase[((size_t)i6 << 6) + lane];
                u64 v7 = rowbase[((size_t)i7 << 6) + lane];
                u64 o = v0 | (h1 ? v1 : 0ULL) | (h2 ? v2 : 0ULL) | (h3 ? v3 : 0ULL)
                           | (h4 ? v4 : 0ULL) | (h5 ? v5 : 0ULL) | (h6 ? v6 : 0ULL) | (h7 ? v7 : 0ULL);
                rvlo |= (u32)o;
                rvhi |= (u32)(o >> 32);
            }
            dlo = (u32)nd; dhi = (u32)(nd >> 32);
        }
    }
    __syncthreads();

    // ---- fused output epilogue ----
    for (int g = tid; g < NBOX * 5; g += 256) {
        const int r = g / 5;
        const int c = g - r * 5;
        bool kept = false;
        if (r < M) kept = ((kbArr[r >> 6] >> (r & 63)) & 1ULL) != 0ULL;
        float vv = 0.0f;
        if (kept) {
            const float* arr = (c == 0) ? sx1 : (c == 1) ? sy1 : (c == 2) ? sx2 : (c == 3) ? sy2 : sconf;
            vv = arr[r];
        }
        out[g] = vv;
    }
}

extern "C" void kernel_launch(void* const* d_in, const int* in_sizes, int n_in,
                              void* d_out, int out_size, void* d_ws, size_t ws_size,
                              hipStream_t stream) {
    const float* raw = (const float*)d_in[0];
    char* ws = (char*)d_ws;
    float* sx1 = (float*)(ws + 0);
    float* sy1 = (float*)(ws + 16384);
    float* sx2 = (float*)(ws + 32768);
    float* sy2 = (float*)(ws + 49152);
    float* sconf = (float*)(ws + 65536);
    int* Mp = (int*)(ws + 81920);
    u64* diagR = (u64*)(ws + 86016);
    u64* mask = (u64*)(ws + 131072);
    int* rank_partial = (int*)(ws + 2228224);
    float* out = (float*)d_out;

    k_rank<<<dim3(16, 16), dim3(256), 0, stream>>>(raw, rank_partial, Mp);
    k_scatter<<<dim3(16), dim3(256), 0, stream>>>(raw, rank_partial, sx1, sy1, sx2, sy2, sconf, Mp);
    k_mask<<<dim3(16, 64), dim3(256), 0, stream>>>(sx1, sy1, sx2, sy2, Mp, mask, diagR);
    k_scan<<<dim3(1), dim3(256), 0, stream>>>(Mp, mask, diagR, sx1, sy1, sx2, sy2, sconf, out);
}